// Round 1
// baseline (205.218 us; speedup 1.0000x reference)
//
#include <hip/hip_runtime.h>
#include <math.h>

#define SQRT3F 1.7320508075688772f

// ---------------------------------------------------------------------------
// Kernel 1: row squared-norms for X (N rows) and Z (M rows), D=64.
// One 64-lane wave per row; coalesced loads; shuffle reduction.
// norms[0..N) = |X_row|^2, norms[N..N+M) = |Z_row|^2
// ---------------------------------------------------------------------------
__global__ __launch_bounds__(256) void norms_kernel(const float* __restrict__ X,
                                                    const float* __restrict__ Z,
                                                    float* __restrict__ norms,
                                                    int N, int M) {
    int wave = (int)((blockIdx.x * blockDim.x + threadIdx.x) >> 6);
    int lane = threadIdx.x & 63;
    int total = N + M;
    if (wave >= total) return;
    const float* src = (wave < N) ? (X + (size_t)wave * 64)
                                  : (Z + (size_t)(wave - N) * 64);
    float v = src[lane];
    float s = v * v;
    #pragma unroll
    for (int off = 32; off > 0; off >>= 1) s += __shfl_down(s, off, 64);
    if (lane == 0) norms[wave] = s;
}

// ---------------------------------------------------------------------------
// Kernel 2: 64x64 output tile per block, 256 threads, 4x4 register blocking.
// LDS tiles stored transposed [k][m] with row stride 68 floats (272 B):
//   - keeps float4 reads 16B-aligned (68 % 4 == 0)
//   - compute reads: A broadcast-16 / <=2-way (free), B 2-phase minimal
//   - staging transpose writes are ~8-way conflicted but happen once per block
// K = D = 64 exactly -> whole K dim resident, no K loop over tiles.
// ---------------------------------------------------------------------------
__global__ __launch_bounds__(256) void matern_kernel(const float* __restrict__ X,
                                                     const float* __restrict__ Z,
                                                     const float* __restrict__ x2,
                                                     const float* __restrict__ z2,
                                                     const float* __restrict__ sigma,
                                                     const float* __restrict__ lengthscale,
                                                     float* __restrict__ out,
                                                     int M) {
    __shared__ float As[64][68];
    __shared__ float Bs[64][68];

    const int t  = threadIdx.x;
    const int m0 = blockIdx.y * 64;
    const int n0 = blockIdx.x * 64;

    // ---- stage: global (row-major [row][k]) -> LDS transposed [k][row] ----
    {
        const int r  = t >> 4;          // 0..15
        const int c4 = (t & 15) << 2;   // 0,4,...,60
        #pragma unroll
        for (int rr = 0; rr < 4; ++rr) {
            const int row = r + rr * 16;
            float4 va = *(const float4*)(X + (size_t)(m0 + row) * 64 + c4);
            As[c4 + 0][row] = va.x;
            As[c4 + 1][row] = va.y;
            As[c4 + 2][row] = va.z;
            As[c4 + 3][row] = va.w;
            float4 vb = *(const float4*)(Z + (size_t)(n0 + row) * 64 + c4);
            Bs[c4 + 0][row] = vb.x;
            Bs[c4 + 1][row] = vb.y;
            Bs[c4 + 2][row] = vb.z;
            Bs[c4 + 3][row] = vb.w;
        }
    }
    __syncthreads();

    const int tx = t & 15;   // output cols n0 + 4*tx .. +3
    const int ty = t >> 4;   // output rows m0 + 4*ty .. +3

    float acc[4][4] = {{0.f}};

    #pragma unroll
    for (int k = 0; k < 64; ++k) {
        float4 a = *(const float4*)&As[k][ty << 2];
        float4 b = *(const float4*)&Bs[k][tx << 2];
        acc[0][0] += a.x * b.x; acc[0][1] += a.x * b.y; acc[0][2] += a.x * b.z; acc[0][3] += a.x * b.w;
        acc[1][0] += a.y * b.x; acc[1][1] += a.y * b.y; acc[1][2] += a.y * b.z; acc[1][3] += a.y * b.w;
        acc[2][0] += a.z * b.x; acc[2][1] += a.z * b.y; acc[2][2] += a.z * b.z; acc[2][3] += a.z * b.w;
        acc[3][0] += a.w * b.x; acc[3][1] += a.w * b.y; acc[3][2] += a.w * b.z; acc[3][3] += a.w * b.w;
    }

    // ---- epilogue: Matern-3/2 ----
    const float s  = sigma[0];
    const float l  = lengthscale[0];
    const float fac = SQRT3F / l;
    const float s2  = s * s;

    float xr[4], zc[4];
    #pragma unroll
    for (int i = 0; i < 4; ++i) xr[i] = x2[m0 + (ty << 2) + i];
    #pragma unroll
    for (int j = 0; j < 4; ++j) zc[j] = z2[n0 + (tx << 2) + j];

    #pragma unroll
    for (int i = 0; i < 4; ++i) {
        float4 res;
        float* rp = (float*)&res;
        #pragma unroll
        for (int j = 0; j < 4; ++j) {
            float sq  = xr[i] + zc[j] - 2.0f * acc[i][j];
            float d   = sqrtf(fmaxf(sq, 1e-12f));
            float val = fac * d;
            rp[j] = s2 * (1.0f + val) * __expf(-val);
        }
        const size_t orow = (size_t)(m0 + (ty << 2) + i) * (size_t)M + n0 + (tx << 2);
        *(float4*)(out + orow) = res;
    }
}

extern "C" void kernel_launch(void* const* d_in, const int* in_sizes, int n_in,
                              void* d_out, int out_size, void* d_ws, size_t ws_size,
                              hipStream_t stream) {
    (void)n_in; (void)out_size; (void)ws_size;
    const float* X   = (const float*)d_in[0];
    const float* Z   = (const float*)d_in[1];
    const float* sig = (const float*)d_in[2];
    const float* len = (const float*)d_in[3];
    float* out = (float*)d_out;

    const int D = 64;
    const int N = in_sizes[0] / D;   // 8192
    const int M = in_sizes[1] / D;   // 4096

    float* norms = (float*)d_ws;     // needs (N+M)*4 = 48 KiB of workspace
    float* x2 = norms;
    float* z2 = norms + N;

    // 1 wave per row, 4 waves per block
    const int total_rows = N + M;
    const int nblocks1 = (total_rows + 3) / 4;
    norms_kernel<<<nblocks1, 256, 0, stream>>>(X, Z, norms, N, M);

    dim3 grid(M / 64, N / 64);
    matern_kernel<<<grid, 256, 0, stream>>>(X, Z, x2, z2, sig, len, out, M);
}

// Round 2
// 187.909 us; speedup vs baseline: 1.0921x; 1.0921x over previous
//
#include <hip/hip_runtime.h>
#include <math.h>

#define SQRT3F 1.7320508075688772f

typedef _Float16 half8 __attribute__((ext_vector_type(8)));
typedef _Float16 half4 __attribute__((ext_vector_type(4)));
typedef float    f32x4 __attribute__((ext_vector_type(4)));

// ---------------------------------------------------------------------------
// Single fused kernel.
//   Block: 256 threads (4 waves), output tile 128x128, K = D = 64 (fully
//   LDS-resident -> exactly ONE __syncthreads per block, no K pipeline).
//
//   Stage: load fp32 X/Z tiles (float4, coalesced), split each value into
//   fp16 hi + lo (hi = (f16)x, lo = (f16)(x - (float)hi); hi+lo carries
//   ~22 mantissa bits ~= fp32), store halves to LDS in [row][k] layout
//   (stride 72 halves = 144 B: 16B-aligned for ds_read_b128). Row squared
//   norms are computed on the fly from the fp32 values via 16-lane
//   __shfl_xor reductions (the 16 lanes of a group hold one row's float4s).
//
//   Compute: dot(X_m, Z_n) ~= Xhi.Zhi + Xhi.Zlo + Xlo.Zhi via
//   v_mfma_f32_16x16x32_f16. Each wave owns a 64x64 sub-tile = 4x4 MFMA
//   tiles; 2 k-chunks x 16 tiles x 3 terms = 96 MFMAs/wave.
//   A-frag: lane holds A[m=lane&15][k=(lane>>4)*8+j]; B-frag mirrors with
//   n=lane&15 (B^T input, rows of Z). C/D: col=lane&15, row=(lane>>4)*4+reg.
//
//   Epilogue: sq = x2[m]+z2[n]-2*dot; Matern-3/2; dword stores (16 lanes of
//   a quad write 64 consecutive bytes; tile spans full cache lines).
// ---------------------------------------------------------------------------
__global__ __launch_bounds__(256, 2)
void matern_mfma_kernel(const float* __restrict__ X,
                        const float* __restrict__ Z,
                        const float* __restrict__ sigma,
                        const float* __restrict__ lengthscale,
                        float* __restrict__ out,
                        int M) {
    __shared__ _Float16 Ah[128][72];
    __shared__ _Float16 Al[128][72];
    __shared__ _Float16 Bh[128][72];
    __shared__ _Float16 Bl[128][72];
    __shared__ float    x2s[128];
    __shared__ float    z2s[128];

    const int t  = threadIdx.x;
    const int n0 = blockIdx.x * 128;   // Z rows / output cols
    const int m0 = blockIdx.y * 128;   // X rows / output rows

    // ---------------- stage + convert + norms ----------------
    // flat float4 index f = t + 256*i ; row = f>>4 (0..127), c4 = f&15.
    // For fixed i, the 16 lanes of a 16-group share one row -> shfl reduce.
    #pragma unroll
    for (int i = 0; i < 8; ++i) {
        const int f   = t + 256 * i;
        const int row = f >> 4;
        const int c4  = f & 15;
        float4 v = *(const float4*)(X + (size_t)(m0 + row) * 64 + c4 * 4);
        _Float16 hx = (_Float16)v.x, hy = (_Float16)v.y, hz = (_Float16)v.z, hw = (_Float16)v.w;
        half4 hv = { hx, hy, hz, hw };
        half4 lv = { (_Float16)(v.x - (float)hx), (_Float16)(v.y - (float)hy),
                     (_Float16)(v.z - (float)hz), (_Float16)(v.w - (float)hw) };
        *(half4*)&Ah[row][c4 * 4] = hv;
        *(half4*)&Al[row][c4 * 4] = lv;
        float ssq = v.x * v.x + v.y * v.y + v.z * v.z + v.w * v.w;
        ssq += __shfl_xor(ssq, 1, 16);
        ssq += __shfl_xor(ssq, 2, 16);
        ssq += __shfl_xor(ssq, 4, 16);
        ssq += __shfl_xor(ssq, 8, 16);
        if ((t & 15) == 0) x2s[row] = ssq;
    }
    #pragma unroll
    for (int i = 0; i < 8; ++i) {
        const int f   = t + 256 * i;
        const int row = f >> 4;
        const int c4  = f & 15;
        float4 v = *(const float4*)(Z + (size_t)(n0 + row) * 64 + c4 * 4);
        _Float16 hx = (_Float16)v.x, hy = (_Float16)v.y, hz = (_Float16)v.z, hw = (_Float16)v.w;
        half4 hv = { hx, hy, hz, hw };
        half4 lv = { (_Float16)(v.x - (float)hx), (_Float16)(v.y - (float)hy),
                     (_Float16)(v.z - (float)hz), (_Float16)(v.w - (float)hw) };
        *(half4*)&Bh[row][c4 * 4] = hv;
        *(half4*)&Bl[row][c4 * 4] = lv;
        float ssq = v.x * v.x + v.y * v.y + v.z * v.z + v.w * v.w;
        ssq += __shfl_xor(ssq, 1, 16);
        ssq += __shfl_xor(ssq, 2, 16);
        ssq += __shfl_xor(ssq, 4, 16);
        ssq += __shfl_xor(ssq, 8, 16);
        if ((t & 15) == 0) z2s[row] = ssq;
    }
    __syncthreads();

    // ---------------- MFMA compute ----------------
    const int lane = t & 63;
    const int w    = t >> 6;
    const int wr   = w >> 1;        // wave row (0..1)
    const int wc   = w & 1;         // wave col (0..1)
    const int lm   = lane & 15;     // m/n within 16-tile
    const int q    = lane >> 4;     // quad (0..3)

    f32x4 acc[4][4];
    #pragma unroll
    for (int a = 0; a < 4; ++a)
        #pragma unroll
        for (int b = 0; b < 4; ++b)
            acc[a][b] = (f32x4){0.f, 0.f, 0.f, 0.f};

    #pragma unroll
    for (int kc = 0; kc < 2; ++kc) {
        const int k = kc * 32 + q * 8;
        half8 ah[4], al[4], bh[4], bl[4];
        #pragma unroll
        for (int mt = 0; mt < 4; ++mt) {
            const int row = wr * 64 + mt * 16 + lm;
            ah[mt] = *(const half8*)&Ah[row][k];
            al[mt] = *(const half8*)&Al[row][k];
        }
        #pragma unroll
        for (int nt = 0; nt < 4; ++nt) {
            const int row = wc * 64 + nt * 16 + lm;
            bh[nt] = *(const half8*)&Bh[row][k];
            bl[nt] = *(const half8*)&Bl[row][k];
        }
        #pragma unroll
        for (int mt = 0; mt < 4; ++mt)
            #pragma unroll
            for (int nt = 0; nt < 4; ++nt) {
                acc[mt][nt] = __builtin_amdgcn_mfma_f32_16x16x32_f16(ah[mt], bh[nt], acc[mt][nt], 0, 0, 0);
                acc[mt][nt] = __builtin_amdgcn_mfma_f32_16x16x32_f16(ah[mt], bl[nt], acc[mt][nt], 0, 0, 0);
                acc[mt][nt] = __builtin_amdgcn_mfma_f32_16x16x32_f16(al[mt], bh[nt], acc[mt][nt], 0, 0, 0);
            }
    }

    // ---------------- epilogue ----------------
    const float s   = sigma[0];
    const float l   = lengthscale[0];
    const float fac = SQRT3F / l;
    const float s2  = s * s;

    #pragma unroll
    for (int mt = 0; mt < 4; ++mt) {
        const int row0 = wr * 64 + mt * 16 + q * 4;
        float xr[4];
        #pragma unroll
        for (int r = 0; r < 4; ++r) xr[r] = x2s[row0 + r];
        #pragma unroll
        for (int nt = 0; nt < 4; ++nt) {
            const int col = wc * 64 + nt * 16 + lm;
            const float zc = z2s[col];
            #pragma unroll
            for (int r = 0; r < 4; ++r) {
                float sq  = xr[r] + zc - 2.0f * acc[mt][nt][r];
                float d   = sqrtf(fmaxf(sq, 1e-12f));
                float val = fac * d;
                out[(size_t)(m0 + row0 + r) * (size_t)M + n0 + col] =
                    s2 * (1.0f + val) * __expf(-val);
            }
        }
    }
}

extern "C" void kernel_launch(void* const* d_in, const int* in_sizes, int n_in,
                              void* d_out, int out_size, void* d_ws, size_t ws_size,
                              hipStream_t stream) {
    (void)n_in; (void)out_size; (void)d_ws; (void)ws_size;
    const float* X   = (const float*)d_in[0];
    const float* Z   = (const float*)d_in[1];
    const float* sig = (const float*)d_in[2];
    const float* len = (const float*)d_in[3];
    float* out = (float*)d_out;

    const int D = 64;
    const int N = in_sizes[0] / D;   // 8192
    const int M = in_sizes[1] / D;   // 4096

    dim3 grid(M / 128, N / 128);
    matern_mfma_kernel<<<grid, 256, 0, stream>>>(X, Z, sig, len, out, M);
}

// Round 4
// 153.818 us; speedup vs baseline: 1.3342x; 1.2216x over previous
//
#include <hip/hip_runtime.h>
#include <math.h>

#define SQRT3F 1.7320508075688772f

typedef _Float16 half8 __attribute__((ext_vector_type(8)));
typedef _Float16 half4 __attribute__((ext_vector_type(4)));
typedef float    f32x4 __attribute__((ext_vector_type(4)));

// ---------------------------------------------------------------------------
// Fused Matern-3/2 Gram kernel.
//   Block: 512 threads (8 waves), output tile 128x128, K = D = 64 fully
//   LDS-resident -> ONE __syncthreads per block. LDS = 74.75 KB -> 2
//   blocks/CU -> 16 waves/CU (round-2 kernel had 8: latency-bound at 21%
//   occupancy with no saturated pipe).
//
//   fp32 accuracy via fp16 hi/lo split (hi=(f16)x, lo=(f16)(x-hi)):
//   dot ~= hi.hi + hi.lo + lo.hi  (3x v_mfma_f32_16x16x32_f16).
//   Row norms fused into staging via 16-lane shfl_xor reductions.
//   Epilogue: sq = x2+z2-2dot, d=v_sqrt_f32(max(sq,1e-12)), v=sqrt3*d/l,
//   out = s^2 (1+v) e^{-v}.
// ---------------------------------------------------------------------------
__global__ __launch_bounds__(512, 4)
void matern_mfma_kernel(const float* __restrict__ X,
                        const float* __restrict__ Z,
                        const float* __restrict__ sigma,
                        const float* __restrict__ lengthscale,
                        float* __restrict__ out,
                        int M) {
    __shared__ _Float16 Ah[128][72];
    __shared__ _Float16 Al[128][72];
    __shared__ _Float16 Bh[128][72];
    __shared__ _Float16 Bl[128][72];
    __shared__ float    x2s[128];
    __shared__ float    z2s[128];

    const int t  = threadIdx.x;
    const int n0 = blockIdx.x * 128;   // Z rows / output cols
    const int m0 = blockIdx.y * 128;   // X rows / output rows

    // ---------------- stage + convert + norms ----------------
    // flat float4 index f = t + 512*i ; row = f>>4 (0..127), c4 = f&15.
    // 16 consecutive threads share a row -> 16-lane shfl_xor reduce for norms.
    {
        float4 vx[4], vz[4];
        #pragma unroll
        for (int i = 0; i < 4; ++i) {
            const int f = t + 512 * i;
            vx[i] = *(const float4*)(X + (size_t)(m0 + (f >> 4)) * 64 + (f & 15) * 4);
        }
        #pragma unroll
        for (int i = 0; i < 4; ++i) {
            const int f = t + 512 * i;
            vz[i] = *(const float4*)(Z + (size_t)(n0 + (f >> 4)) * 64 + (f & 15) * 4);
        }
        #pragma unroll
        for (int i = 0; i < 4; ++i) {
            const int f   = t + 512 * i;
            const int row = f >> 4;
            const int c4  = f & 15;
            float4 v = vx[i];
            _Float16 hx = (_Float16)v.x, hy = (_Float16)v.y, hz = (_Float16)v.z, hw = (_Float16)v.w;
            half4 hv = { hx, hy, hz, hw };
            half4 lv = { (_Float16)(v.x - (float)hx), (_Float16)(v.y - (float)hy),
                         (_Float16)(v.z - (float)hz), (_Float16)(v.w - (float)hw) };
            *(half4*)&Ah[row][c4 * 4] = hv;
            *(half4*)&Al[row][c4 * 4] = lv;
            float ssq = v.x * v.x + v.y * v.y + v.z * v.z + v.w * v.w;
            ssq += __shfl_xor(ssq, 1, 16);
            ssq += __shfl_xor(ssq, 2, 16);
            ssq += __shfl_xor(ssq, 4, 16);
            ssq += __shfl_xor(ssq, 8, 16);
            if ((t & 15) == 0) x2s[row] = ssq;
        }
        #pragma unroll
        for (int i = 0; i < 4; ++i) {
            const int f   = t + 512 * i;
            const int row = f >> 4;
            const int c4  = f & 15;
            float4 v = vz[i];
            _Float16 hx = (_Float16)v.x, hy = (_Float16)v.y, hz = (_Float16)v.z, hw = (_Float16)v.w;
            half4 hv = { hx, hy, hz, hw };
            half4 lv = { (_Float16)(v.x - (float)hx), (_Float16)(v.y - (float)hy),
                         (_Float16)(v.z - (float)hz), (_Float16)(v.w - (float)hw) };
            *(half4*)&Bh[row][c4 * 4] = hv;
            *(half4*)&Bl[row][c4 * 4] = lv;
            float ssq = v.x * v.x + v.y * v.y + v.z * v.z + v.w * v.w;
            ssq += __shfl_xor(ssq, 1, 16);
            ssq += __shfl_xor(ssq, 2, 16);
            ssq += __shfl_xor(ssq, 4, 16);
            ssq += __shfl_xor(ssq, 8, 16);
            if ((t & 15) == 0) z2s[row] = ssq;
        }
    }
    __syncthreads();

    // ---------------- MFMA compute ----------------
    // 8 waves: 2 wave-rows x 4 wave-cols; each wave owns 64(m) x 32(n).
    const int lane = t & 63;
    const int w    = t >> 6;
    const int wr   = w >> 2;        // 0..1
    const int wc   = w & 3;         // 0..3
    const int lm   = lane & 15;
    const int q    = lane >> 4;

    f32x4 acc[4][2];
    #pragma unroll
    for (int a = 0; a < 4; ++a)
        #pragma unroll
        for (int b = 0; b < 2; ++b)
            acc[a][b] = (f32x4){0.f, 0.f, 0.f, 0.f};

    #pragma unroll
    for (int kc = 0; kc < 2; ++kc) {
        const int k = kc * 32 + q * 8;
        half8 ah[4], al[4], bh[2], bl[2];
        #pragma unroll
        for (int mt = 0; mt < 4; ++mt) {
            const int row = wr * 64 + mt * 16 + lm;
            ah[mt] = *(const half8*)&Ah[row][k];
            al[mt] = *(const half8*)&Al[row][k];
        }
        #pragma unroll
        for (int nt = 0; nt < 2; ++nt) {
            const int row = wc * 32 + nt * 16 + lm;
            bh[nt] = *(const half8*)&Bh[row][k];
            bl[nt] = *(const half8*)&Bl[row][k];
        }
        #pragma unroll
        for (int mt = 0; mt < 4; ++mt)
            #pragma unroll
            for (int nt = 0; nt < 2; ++nt) {
                acc[mt][nt] = __builtin_amdgcn_mfma_f32_16x16x32_f16(ah[mt], bh[nt], acc[mt][nt], 0, 0, 0);
                acc[mt][nt] = __builtin_amdgcn_mfma_f32_16x16x32_f16(ah[mt], bl[nt], acc[mt][nt], 0, 0, 0);
                acc[mt][nt] = __builtin_amdgcn_mfma_f32_16x16x32_f16(al[mt], bh[nt], acc[mt][nt], 0, 0, 0);
            }
    }

    // ---------------- epilogue ----------------
    const float s   = sigma[0];
    const float l   = lengthscale[0];
    const float fac = SQRT3F / l;
    const float s2  = s * s;

    #pragma unroll
    for (int mt = 0; mt < 4; ++mt) {
        const int row0 = wr * 64 + mt * 16 + q * 4;
        float xr[4];
        #pragma unroll
        for (int r = 0; r < 4; ++r) xr[r] = x2s[row0 + r];
        #pragma unroll
        for (int nt = 0; nt < 2; ++nt) {
            const int col = wc * 32 + nt * 16 + lm;
            const float zc = z2s[col];
            #pragma unroll
            for (int r = 0; r < 4; ++r) {
                float sq  = xr[r] + zc - 2.0f * acc[mt][nt][r];
                float d   = __builtin_amdgcn_sqrtf(fmaxf(sq, 1e-12f));
                float val = fac * d;
                out[(size_t)(m0 + row0 + r) * (size_t)M + n0 + col] =
                    s2 * (1.0f + val) * __expf(-val);
            }
        }
    }
}

extern "C" void kernel_launch(void* const* d_in, const int* in_sizes, int n_in,
                              void* d_out, int out_size, void* d_ws, size_t ws_size,
                              hipStream_t stream) {
    (void)n_in; (void)out_size; (void)d_ws; (void)ws_size;
    const float* X   = (const float*)d_in[0];
    const float* Z   = (const float*)d_in[1];
    const float* sig = (const float*)d_in[2];
    const float* len = (const float*)d_in[3];
    float* out = (float*)d_out;

    const int D = 64;
    const int N = in_sizes[0] / D;   // 8192
    const int M = in_sizes[1] / D;   // 4096

    dim3 grid(M / 128, N / 128);
    matern_mfma_kernel<<<grid, 512, 0, stream>>>(X, Z, sig, len, out, M);
}